// Round 21
// baseline (311.035 us; speedup 1.0000x reference)
//
#include <hip/hip_runtime.h>
#include <hip/hip_fp16.h>

#define N_NODES 50000
#define NEDGE   500000
#define HEADS   8
#define FEAT    16
#define HF      128   // HEADS*FEAT
#define UST     64    // u row stride in FLOATS: 128 fp16 = 256B

typedef __attribute__((ext_vector_type(8))) _Float16 half8;
typedef __attribute__((ext_vector_type(4))) float floatx4;

__device__ __forceinline__ unsigned pkh2(float a, float b) {
  __half2 h = __floats2half2_rn(a, b);
  return *(unsigned*)&h;
}

// ===== prep: Wt2[side][col][k] fp16, col 0-127 = Wv, 128-135 = Wfk, 136-143 = Wfq
__global__ __launch_bounds__(256)
void prep_wt2_kernel(const float* __restrict__ W, const float* __restrict__ wf,
                     __half* __restrict__ Wt2, float* __restrict__ bias16) {
  int side = blockIdx.x;
  const float* Wp  = W + (size_t)side * 16384;
  const float* wfk = wf + (size_t)(side == 0 ? 1 : 3) * 1040;  // wslot(0,0,1)/(0,1,1)
  const float* wfq = wf + (size_t)(side == 0 ? 2 : 0) * 1040;  // wslot(0,1,0)/(0,0,0)
  __half* o = Wt2 + (size_t)side * 144 * 128;
  for (int j = threadIdx.x; j < 144 * 128; j += 256) {
    int col = j >> 7, k = j & 127;
    float v = (col < 128) ? Wp[k * 128 + col]
            : (col < 136) ? wfk[k * 8 + (col - 128)]
                          : wfq[k * 8 + (col - 136)];
    o[j] = __float2half(v);
  }
  if (threadIdx.x < 16) {
    int c = threadIdx.x;
    bias16[side * 16 + c] = (c < 8) ? wfk[1024 + c] : wfq[1024 + (c - 8)];
  }
}

// ========== MFMA GEMM + fused qk: u(fp16), k(fp32), q(fp32) ; grid (782, 2) ==========
__global__ __launch_bounds__(256)
void gemm_mfma_kernel(const float* __restrict__ xa, const int* __restrict__ idxa,
                      const float* __restrict__ xb, const int* __restrict__ idxb,
                      const __half* __restrict__ Wt2, const float* __restrict__ bias,
                      const float* __restrict__ bias16,
                      float* __restrict__ ua, float* __restrict__ ub,
                      float* __restrict__ kb0, float* __restrict__ kb1,
                      float* __restrict__ qb1, float* __restrict__ qb0, int nrows) {
  const int side = blockIdx.y;
  const float* x  = side ? xb : xa;
  const int* idx  = side ? idxb : idxa;
  const __half* Wtp = Wt2 + (size_t)side * 144 * 128;
  const float* bp = bias + side * HF;
  const float* b8 = bias16 + side * 16;
  float* uout = side ? ub : ua;
  float* kout = side ? kb1 : kb0;
  float* qout = side ? qb0 : qb1;

  __shared__ __align__(16) unsigned short sm[26624];  // A 16KB | Wt2 36KB
  char* Asm = (char*)sm;
  char* Wsm = (char*)(sm + 8192);
  const int tid = threadIdx.x;
  const int w = tid >> 6, lane = tid & 63;
  const int row0 = blockIdx.x * 64;

  #pragma unroll
  for (int p = 0; p < 9; ++p) {
    int i = p * 256 + tid;
    int col = i >> 4, kp = i & 15;
    float4 v = *(const float4*)(Wtp + col * 128 + kp * 8);
    int dst = (col * 256 + kp * 16) ^ ((col & 7) << 4);
    *(float4*)(Wsm + dst) = v;
  }
  {
    int r = tid >> 2;
    int rr = row0 + r;
    int g = (rr < nrows) ? (idx ? idx[rr] : rr) : 0;
    const float* xp = x + (size_t)g * 128 + (tid & 3) * 8;
    #pragma unroll
    for (int p = 0; p < 4; ++p) {
      float4 v0 = *(const float4*)(xp + p * 32);
      float4 v1 = *(const float4*)(xp + p * 32 + 4);
      uint4 o;
      o.x = pkh2(v0.x, v0.y); o.y = pkh2(v0.z, v0.w);
      o.z = pkh2(v1.x, v1.y); o.w = pkh2(v1.z, v1.w);
      int k0 = (tid & 3) * 8 + p * 32;
      int dst = (r * 256 + k0 * 2) ^ ((r & 7) << 4);
      *(uint4*)(Asm + dst) = o;
    }
  }
  __syncthreads();

  floatx4 acc[9];
  #pragma unroll
  for (int t = 0; t < 8; ++t) {
    float b = bp[t * 16 + (lane & 15)];
    acc[t] = (floatx4){b, b, b, b};
  }
  {
    float b = b8[lane & 15];
    acc[8] = (floatx4){b, b, b, b};
  }

  const int lrow = lane & 15, lk = lane >> 4;
  #pragma unroll
  for (int kb = 0; kb < 4; ++kb) {
    int r = w * 16 + lrow;
    int abyte = (r * 256 + kb * 64 + lk * 16) ^ ((r & 7) << 4);
    half8 af = *(const half8*)(Asm + abyte);
    #pragma unroll
    for (int t = 0; t < 9; ++t) {
      int c = t * 16 + lrow;
      int bbyte = (c * 256 + kb * 64 + lk * 16) ^ ((c & 7) << 4);
      half8 bf = *(const half8*)(Wsm + bbyte);
      acc[t] = __builtin_amdgcn_mfma_f32_16x16x32_f16(af, bf, acc[t], 0, 0, 0);
    }
  }

  unsigned short* up = (unsigned short*)uout;
  #pragma unroll
  for (int j = 0; j < 4; ++j) {
    int rr = row0 + w * 16 + (lane >> 4) * 4 + j;
    if (rr < nrows) {
      #pragma unroll
      for (int t = 0; t < 8; ++t) {
        __half h = __float2half(acc[t][j]);
        up[(size_t)rr * 128 + t * 16 + (lane & 15)] = *(unsigned short*)&h;
      }
      int col = lane & 15;
      if (col < 8) kout[(size_t)rr * 8 + col] = acc[8][j];
      else         qout[(size_t)rr * 8 + (col - 8)] = acc[8][j];
    }
  }
}

// ================= fold Wf = Wv @ Wqk [Kx,8], bias bf = bv@Wqk + bqk =================
__global__ __launch_bounds__(256)
void fold_kernel(const float* __restrict__ l1_Wv, const float* __restrict__ l1_bv,
                 const float* __restrict__ l1_Wq, const float* __restrict__ l1_bq,
                 const float* __restrict__ l1_Wk, const float* __restrict__ l1_bk,
                 const float* __restrict__ l2_Wv, const float* __restrict__ l2_bv,
                 const float* __restrict__ l2_Wq, const float* __restrict__ l2_bq,
                 const float* __restrict__ l2_Wk, const float* __restrict__ l2_bk,
                 float* __restrict__ outbuf) {
  int b = blockIdx.x;
  int layer = b >> 2, rel = (b >> 1) & 1, qk = b & 1;
  int Kx = (layer == 0) ? 128 : 16;
  const float* Wv = ((layer == 0) ? l1_Wv : l2_Wv) + (size_t)rel * Kx * HF;
  const float* bv = ((layer == 0) ? l1_bv : l2_bv) + rel * HF;
  const float* Wqk = ((layer == 0) ? (qk ? l1_Wk : l1_Wq) : (qk ? l2_Wk : l2_Wq)) + (size_t)rel * HF * 8;
  const float* bqk = ((layer == 0) ? (qk ? l1_bk : l1_bq) : (qk ? l2_bk : l2_bq)) + rel * 8;
  float* o = outbuf + (size_t)b * 1040;
  for (int t = threadIdx.x; t < Kx * 8; t += 256) {
    int row = t >> 3, c = t & 7;
    float acc = 0.f;
    for (int j = 0; j < HF; ++j) acc += Wv[row * HF + j] * Wqk[j * 8 + c];
    o[t] = acc;
  }
  for (int t = threadIdx.x; t < 8; t += 256) {
    float acc = bqk[t];
    for (int j = 0; j < HF; ++j) acc += bv[j] * Wqk[j * 8 + t];
    o[Kx * 8 + t] = acc;
  }
}

// ========== L2 qk: k2 = x@Wfk, q = x@Wfq ([n,16] -> [n,8] each) ; grid (nb,2) ==========
__global__ __launch_bounds__(256)
void qk16_kernel(const float* __restrict__ xA, const float* __restrict__ xB,
                 const float* __restrict__ WfkA, const float* __restrict__ WfqA,
                 const float* __restrict__ WfkB, const float* __restrict__ WfqB,
                 float* __restrict__ k2a, float* __restrict__ k2b,
                 float* __restrict__ qA, float* __restrict__ qB, int n) {
  const int side = blockIdx.y;
  const float* x   = side ? xB : xA;
  const float* Wfk = side ? WfkB : WfkA;
  const float* Wfq = side ? WfqB : WfqA;
  float* k2  = side ? k2b : k2a;
  float* qout = side ? qB : qA;
  __shared__ float Wk[136], Wq[136];
  const int tid = threadIdx.x;
  for (int i = tid; i < 136; i += 256) { Wk[i] = Wfk[i]; Wq[i] = Wfq[i]; }
  __syncthreads();
  int row = blockIdx.x * 32 + (tid >> 3), col = tid & 7;
  if (row >= n) return;
  const float* xr = x + (size_t)row * 16;
  float ak = Wk[128 + col], aq = Wq[128 + col];
  #pragma unroll
  for (int j4 = 0; j4 < 4; ++j4) {
    float4 v = *(const float4*)(xr + j4 * 4);
    float xv[4] = {v.x, v.y, v.z, v.w};
    #pragma unroll
    for (int j = 0; j < 4; ++j) {
      ak += xv[j] * Wk[(j4 * 4 + j) * 8 + col];
      aq += xv[j] * Wq[(j4 * 4 + j) * 8 + col];
    }
  }
  k2[row * 8 + col] = ak;
  qout[row * 8 + col] = aq;
}

// ================= batched CSR build (both relations at once) =================
__global__ __launch_bounds__(256)
void hist2_kernel(const int* __restrict__ dst0, const int* __restrict__ dst1,
                  int* __restrict__ cnt) {
  int e = blockIdx.x * 256 + threadIdx.x;
  if (e < NEDGE) atomicAdd(&cnt[dst0[e]], 1);
  else if (e < 2 * NEDGE) atomicAdd(&cnt[N_NODES + dst1[e - NEDGE]], 1);
}

__global__ __launch_bounds__(256)
void scan_bsum_kernel(const int* __restrict__ cnt, int* __restrict__ bsum, int n) {
  __shared__ int s[256];
  int i = blockIdx.x * 256 + threadIdx.x;
  s[threadIdx.x] = (i < n) ? cnt[i] : 0;
  __syncthreads();
  for (int o = 128; o > 0; o >>= 1) {
    if (threadIdx.x < o) s[threadIdx.x] += s[threadIdx.x + o];
    __syncthreads();
  }
  if (threadIdx.x == 0) bsum[blockIdx.x] = s[0];
}

__global__ __launch_bounds__(512)
void scan_offsets_kernel(int* __restrict__ bsum, int nb) {
  __shared__ int s[512];
  int t = threadIdx.x;
  s[t] = (t < nb) ? bsum[t] : 0;
  __syncthreads();
  for (int o = 1; o < 512; o <<= 1) {
    int v = (t >= o) ? s[t - o] : 0;
    __syncthreads();
    s[t] += v;
    __syncthreads();
  }
  if (t < nb) bsum[t] = (t == 0) ? 0 : s[t - 1];
}

__global__ __launch_bounds__(256)
void scan_final_kernel(const int* __restrict__ cnt, const int* __restrict__ boff,
                       int* __restrict__ row_start, int n) {
  __shared__ int s[256];
  int t = threadIdx.x, i = blockIdx.x * 256 + t;
  int v = (i < n) ? cnt[i] : 0;
  s[t] = v;
  __syncthreads();
  for (int o = 1; o < 256; o <<= 1) {
    int w = (t >= o) ? s[t - o] : 0;
    __syncthreads();
    s[t] += w;
    __syncthreads();
  }
  if (i < n)  row_start[i] = boff[blockIdx.x] + s[t] - v;
  if (i == n - 1) row_start[n] = boff[blockIdx.x] + s[t];
}

__global__ __launch_bounds__(256)
void csr_scatter2_kernel(const int* __restrict__ s0, const int* __restrict__ d0,
                         const int* __restrict__ s1, const int* __restrict__ d1,
                         const int* __restrict__ rs, int* __restrict__ fill,
                         int* __restrict__ cs) {
  int e = blockIdx.x * 256 + threadIdx.x;
  if (e >= 2 * NEDGE) return;
  int rel = (e >= NEDGE);
  int ee = rel ? e - NEDGE : e;
  int d = rel ? d1[ee] : d0[ee];
  int s = rel ? s1[ee] : s0[ee];
  int key = rel * N_NODES + d;
  int pos = rs[key] + atomicAdd(&fill[key], 1);
  cs[pos] = s;
}

// ========= L1 GAT aggregation, 32 lanes/node, fp16 u (uint2/lane), separate fp32 k ====
__global__ __launch_bounds__(256)
void node_agg2_kernel(const int* __restrict__ rs, const int* __restrict__ cs,
                      const float* __restrict__ u0, const float* __restrict__ u1,
                      const float* __restrict__ kb0, const float* __restrict__ kb1,
                      const float* __restrict__ qt0, const float* __restrict__ qt1,
                      float* __restrict__ out0, float* __restrict__ out1, int elu) {
  int grp  = (blockIdx.x * 256 + threadIdx.x) >> 5;
  int lane = threadIdx.x & 31;
  if (grp >= 2 * N_NODES) return;
  int rel = grp >= N_NODES;
  int node = grp - (rel ? N_NODES : 0);
  const float* ut = rel ? u1 : u0;
  const float* kb = rel ? kb1 : kb0;
  const float* qt = rel ? qt1 : qt0;
  float* out      = rel ? out1 : out0;

  int e0 = rs[grp], e1 = rs[grp + 1];
  const int hd = lane >> 2;
  float qh = qt[node * 8 + hd];
  float den = 0.f;
  float4 acc = make_float4(0.f, 0.f, 0.f, 0.f);

  int e = e0;
  for (; e + 7 < e1; e += 8) {
    int s[8];
    #pragma unroll
    for (int j = 0; j < 8; ++j) s[j] = cs[e + j];
    uint2 uv[8]; float kv[8];
    #pragma unroll
    for (int j = 0; j < 8; ++j) {
      uv[j] = *(const uint2*)((const char*)(ut + (size_t)s[j] * UST) + lane * 8);
      kv[j] = kb[s[j] * 8 + hd];
    }
    #pragma unroll
    for (int j = 0; j < 8; ++j) {
      float sc = kv[j] + qh; sc = sc > 0.f ? sc : 0.2f * sc;
      float ex = __expf(sc);
      den += ex;
      float2 f01 = __half22float2(*(__half2*)&uv[j].x);
      float2 f23 = __half22float2(*(__half2*)&uv[j].y);
      acc.x += ex * f01.x; acc.y += ex * f01.y;
      acc.z += ex * f23.x; acc.w += ex * f23.y;
    }
  }
  for (; e < e1; ++e) {
    int s0 = cs[e];
    uint2 uvv = *(const uint2*)((const char*)(ut + (size_t)s0 * UST) + lane * 8);
    float kv = kb[s0 * 8 + hd];
    float sc = kv + qh; sc = sc > 0.f ? sc : 0.2f * sc;
    float ex = __expf(sc);
    den += ex;
    float2 f01 = __half22float2(*(__half2*)&uvv.x);
    float2 f23 = __half22float2(*(__half2*)&uvv.y);
    acc.x += ex * f01.x; acc.y += ex * f01.y;
    acc.z += ex * f23.x; acc.w += ex * f23.y;
  }
  float inv = den > 0.f ? 1.f / den : 0.f;
  float4 r = make_float4(acc.x * inv, acc.y * inv, acc.z * inv, acc.w * inv);
  #pragma unroll
  for (int m = 4; m <= 16; m <<= 1) {
    r.x += __shfl_xor(r.x, m); r.y += __shfl_xor(r.y, m);
    r.z += __shfl_xor(r.z, m); r.w += __shfl_xor(r.w, m);
  }
  r.x *= 0.125f; r.y *= 0.125f; r.z *= 0.125f; r.w *= 0.125f;
  if (elu) {
    r.x = r.x > 0.f ? r.x : expm1f(r.x);
    r.y = r.y > 0.f ? r.y : expm1f(r.y);
    r.z = r.z > 0.f ? r.z : expm1f(r.z);
    r.w = r.w > 0.f ? r.w : expm1f(r.w);
  }
  if (lane < 4) *(float4*)&out[(size_t)node * FEAT + lane * 4] = r;
}

// ========= L2 GAT aggregation via z-trick, SPLIT BY RELATION (grid 6250 x 2) =========
// R20 counter evidence: Occupancy 46% with LDS=20.5KB -> 7 blocks/CU (LDS cap).
// Each 32-lane group uses only ONE relation's Wt; blockIdx.y=rel stages 8KB not
// 16KB -> ~12.5KB/block -> 12 blocks/CU -> ~75% occupancy for the gather chain.
__global__ __launch_bounds__(256)
void agg_l2z_kernel(const int* __restrict__ rs, const int* __restrict__ cs,
                    const float* __restrict__ xA, const float* __restrict__ xB,
                    const float* __restrict__ k2a, const float* __restrict__ k2b,
                    const float* __restrict__ qt0, const float* __restrict__ qt1,
                    const float* __restrict__ Wv, const float* __restrict__ bv,
                    float* __restrict__ out) {
  const int rel = blockIdx.y;
  __shared__ float Wt_lds[128 * 16];      // [(h*16+j)*16+o] 8 KB (this rel only)
  __shared__ float z_lds[8][128];         // 4 KB
  __shared__ float bvs[16];
  const int tid = threadIdx.x;
  for (int i = tid; i < 2048; i += 256) {
    int j = i >> 7, c = i & 127, h = c >> 4, o = c & 15;
    Wt_lds[(h * 16 + j) * 16 + o] = Wv[rel * 2048 + i];
  }
  if (tid < 16) {
    float s = 0.f;
    #pragma unroll
    for (int h = 0; h < 8; ++h) s += bv[rel * 128 + h * 16 + tid];
    bvs[tid] = s;
  }
  __syncthreads();

  int node = blockIdx.x * 8 + (tid >> 5);     // 6250*8 = 50000 exactly
  int lane = tid & 31;
  int gl   = tid >> 5;
  const float* x  = rel ? xB : xA;
  const float* k2 = rel ? k2b : k2a;
  const float* qt = rel ? qt1 : qt0;
  int grp = rel * N_NODES + node;

  int e0 = rs[grp], e1 = rs[grp + 1];
  const int h = lane >> 2, jg = (lane & 3) * 4;
  float qh = qt[node * 8 + h];
  float den = 0.f;
  float4 z = make_float4(0.f, 0.f, 0.f, 0.f);

  int e = e0;
  for (; e + 7 < e1; e += 8) {
    int s[8];
    #pragma unroll
    for (int j = 0; j < 8; ++j) s[j] = cs[e + j];
    float kv[8]; float4 xv[8];
    #pragma unroll
    for (int j = 0; j < 8; ++j) {
      kv[j] = k2[s[j] * 8 + h];
      xv[j] = *(const float4*)&x[(size_t)s[j] * 16 + jg];
    }
    #pragma unroll
    for (int j = 0; j < 8; ++j) {
      float sc = kv[j] + qh; sc = sc > 0.f ? sc : 0.2f * sc;
      float ex = __expf(sc);
      den += ex;
      z.x += ex * xv[j].x; z.y += ex * xv[j].y;
      z.z += ex * xv[j].z; z.w += ex * xv[j].w;
    }
  }
  for (; e < e1; ++e) {
    int s0 = cs[e];
    float kv = k2[s0 * 8 + h];
    float4 xv = *(const float4*)&x[(size_t)s0 * 16 + jg];
    float sc = kv + qh; sc = sc > 0.f ? sc : 0.2f * sc;
    float ex = __expf(sc);
    den += ex;
    z.x += ex * xv.x; z.y += ex * xv.y; z.z += ex * xv.z; z.w += ex * xv.w;
  }
  float inv = den > 0.f ? 1.f / den : 0.f;
  z.x *= inv; z.y *= inv; z.z *= inv; z.w *= inv;
  *(float4*)&z_lds[gl][h * 16 + jg] = z;
  // no barrier: z_lds[gl] write+read are wave-local

  const int o = lane & 15, half = lane >> 4;
  float acc = 0.f;
  #pragma unroll
  for (int hg = 0; hg < 4; ++hg) {
    int h2 = half * 4 + hg;
    const float* zr = &z_lds[gl][h2 * 16];
    float4 z0 = *(const float4*)zr;
    float4 z1 = *(const float4*)(zr + 4);
    float4 z2 = *(const float4*)(zr + 8);
    float4 z3 = *(const float4*)(zr + 12);
    const float* wb = &Wt_lds[h2 * 256 + o];
    acc += z0.x * wb[0]   + z0.y * wb[16]  + z0.z * wb[32]  + z0.w * wb[48]
         + z1.x * wb[64]  + z1.y * wb[80]  + z1.z * wb[96]  + z1.w * wb[112]
         + z2.x * wb[128] + z2.y * wb[144] + z2.z * wb[160] + z2.w * wb[176]
         + z3.x * wb[192] + z3.y * wb[208] + z3.z * wb[224] + z3.w * wb[240];
  }
  acc += __shfl_xor(acc, 16);
  if (lane < 16) {
    float r = 0.125f * (acc + ((e1 > e0) ? bvs[o] : 0.f));
    float* ob = out + (rel ? 0 : (size_t)N_NODES * FEAT);
    ob[(size_t)node * FEAT + o] = r;
  }
}

extern "C" void kernel_launch(void* const* d_in, const int* in_sizes, int n_in,
                              void* d_out, int out_size, void* d_ws, size_t ws_size,
                              hipStream_t stream) {
  const int* idx_a  = (const int*)d_in[0];
  const int* idx_b  = (const int*)d_in[1];
  const int* src_r0 = (const int*)d_in[2];
  const int* dst_r0 = (const int*)d_in[3];
  const int* src_r1 = (const int*)d_in[4];
  const int* dst_r1 = (const int*)d_in[5];
  const float* emb_a = (const float*)d_in[6];
  const float* emb_b = (const float*)d_in[7];
  const float* l1_Wv = (const float*)d_in[8];
  const float* l1_bv = (const float*)d_in[9];
  const float* l1_Wq = (const float*)d_in[10];
  const float* l1_bq = (const float*)d_in[11];
  const float* l1_Wk = (const float*)d_in[12];
  const float* l1_bk = (const float*)d_in[13];
  const float* l2_Wv = (const float*)d_in[14];
  const float* l2_bv = (const float*)d_in[15];
  const float* l2_Wq = (const float*)d_in[16];
  const float* l2_bq = (const float*)d_in[17];
  const float* l2_Wk = (const float*)d_in[18];
  const float* l2_bk = (const float*)d_in[19];
  float* out = (float*)d_out;

  char* ws = (char*)d_ws;
  size_t off = 0;
  auto alloc = [&](size_t bytes) {
    void* p = ws + off; off += (bytes + 255) & ~255ULL; return p;
  };
  float*  u0    = (float*)alloc((size_t)N_NODES * UST * 4);
  float*  u1    = (float*)alloc((size_t)N_NODES * UST * 4);
  __half* Wt2   = (__half*)alloc(2 * 144 * 128 * 2);        // [Wv|Wfk|Wfq] fp16
  float*  b16   = (float*)alloc(2 * 16 * 4);
  float*  kb0   = (float*)alloc((size_t)N_NODES * HEADS * 4);
  float*  kb1   = (float*)alloc((size_t)N_NODES * HEADS * 4);
  float*  qb0   = (float*)alloc((size_t)N_NODES * HEADS * 4);
  float*  qb1   = (float*)alloc((size_t)N_NODES * HEADS * 4);
  float*  k2a   = (float*)alloc((size_t)N_NODES * HEADS * 4);
  float*  k2b   = (float*)alloc((size_t)N_NODES * HEADS * 4);
  float*  xA    = (float*)alloc((size_t)N_NODES * FEAT * 4);
  float*  xB    = (float*)alloc((size_t)N_NODES * FEAT * 4);
  int*    rs    = (int*)  alloc((size_t)(2 * N_NODES + 1) * 4);
  int*    cs    = (int*)  alloc((size_t)2 * NEDGE * 4);
  int*    cnt   = (int*)  alloc((size_t)4 * N_NODES * 4);
  int*    bsum  = (int*)  alloc(512 * 4);
  float*  wf    = (float*)alloc(8 * 1040 * 4);

  dim3 blk(256);
  const int n2 = 2 * N_NODES;
  int* fill = cnt + n2;
  const int nScanBlk  = (n2 + 255) / 256;
  const int nEdgeBlk2 = (2 * NEDGE + 255) / 256;
  const int nAggBlk   = (n2 + 7) / 8;              // node_agg2: 12500
  const int nAggL2    = N_NODES / 8;               // agg_l2z: 6250 x 2
  const int nGemmBlk64 = (N_NODES + 63) / 64;      // 782
  const int nQk16Blk   = (N_NODES + 31) / 32;

  fold_kernel<<<8, blk, 0, stream>>>(l1_Wv, l1_bv, l1_Wq, l1_bq, l1_Wk, l1_bk,
                                     l2_Wv, l2_bv, l2_Wq, l2_bq, l2_Wk, l2_bk, wf);
  prep_wt2_kernel<<<2, blk, 0, stream>>>(l1_Wv, wf, Wt2, b16);
  auto wslot = [&](int layer, int rel, int qk) {
    return wf + (size_t)((layer << 2) | (rel << 1) | qk) * 1040;
  };

  hipMemsetAsync(cnt, 0, (size_t)2 * n2 * 4, stream);
  hist2_kernel<<<nEdgeBlk2, blk, 0, stream>>>(dst_r0, dst_r1, cnt);
  scan_bsum_kernel<<<nScanBlk, blk, 0, stream>>>(cnt, bsum, n2);
  scan_offsets_kernel<<<1, dim3(512), 0, stream>>>(bsum, nScanBlk);
  scan_final_kernel<<<nScanBlk, blk, 0, stream>>>(cnt, bsum, rs, n2);
  csr_scatter2_kernel<<<nEdgeBlk2, blk, 0, stream>>>(src_r0, dst_r0, src_r1, dst_r1,
                                                     rs, fill, cs);

  // ---- layer 1 (u + k + q all from one MFMA kernel) ----
  {
    gemm_mfma_kernel<<<dim3(nGemmBlk64, 2), blk, 0, stream>>>(
        emb_a, idx_a, emb_b, idx_b, Wt2, l1_bv, b16,
        u0, u1, kb0, kb1, qb1, qb0, N_NODES);
    node_agg2_kernel<<<nAggBlk, blk, 0, stream>>>(rs, cs, u0, u1, kb0, kb1,
                                                  qb0, qb1, xB, xA, 1);
  }
  // ---- layer 2 (z-trick, rel-split grid) ----
  {
    qk16_kernel<<<dim3(nQk16Blk, 2), blk, 0, stream>>>(
        xA, xB,
        wslot(1,0,1), wslot(1,1,0), wslot(1,1,1), wslot(1,0,0),
        k2a, k2b, qb1, qb0, N_NODES);
    agg_l2z_kernel<<<dim3(nAggL2, 2), blk, 0, stream>>>(
        rs, cs, xA, xB, k2a, k2b, qb0, qb1, l2_Wv, l2_bv, out);
  }
}

// Round 22
// 268.787 us; speedup vs baseline: 1.1572x; 1.1572x over previous
//
#include <hip/hip_runtime.h>
#include <hip/hip_fp16.h>

#define N_NODES 50000
#define NEDGE   500000
#define HEADS   8
#define FEAT    16
#define HF      128   // HEADS*FEAT
#define UST     64    // u row stride in FLOATS: 128 fp16 = 256B

typedef __attribute__((ext_vector_type(8))) _Float16 half8;
typedef __attribute__((ext_vector_type(4))) float floatx4;

__device__ __forceinline__ unsigned pkh2(float a, float b) {
  __half2 h = __floats2half2_rn(a, b);
  return *(unsigned*)&h;
}

// ===== prep: Wt2[side][col][k] fp16, col 0-127 = Wv, 128-135 = Wfk, 136-143 = Wfq
__global__ __launch_bounds__(256)
void prep_wt2_kernel(const float* __restrict__ W, const float* __restrict__ wf,
                     __half* __restrict__ Wt2, float* __restrict__ bias16) {
  int side = blockIdx.x;
  const float* Wp  = W + (size_t)side * 16384;
  const float* wfk = wf + (size_t)(side == 0 ? 1 : 3) * 1040;
  const float* wfq = wf + (size_t)(side == 0 ? 2 : 0) * 1040;
  __half* o = Wt2 + (size_t)side * 144 * 128;
  for (int j = threadIdx.x; j < 144 * 128; j += 256) {
    int col = j >> 7, k = j & 127;
    float v = (col < 128) ? Wp[k * 128 + col]
            : (col < 136) ? wfk[k * 8 + (col - 128)]
                          : wfq[k * 8 + (col - 136)];
    o[j] = __float2half(v);
  }
  if (threadIdx.x < 16) {
    int c = threadIdx.x;
    bias16[side * 16 + c] = (c < 8) ? wfk[1024 + c] : wfq[1024 + (c - 8)];
  }
}

// ========== MFMA GEMM + fused qk: u(fp16), k(fp32), q(fp32) ; grid (782, 2) ==========
__global__ __launch_bounds__(256)
void gemm_mfma_kernel(const float* __restrict__ xa, const int* __restrict__ idxa,
                      const float* __restrict__ xb, const int* __restrict__ idxb,
                      const __half* __restrict__ Wt2, const float* __restrict__ bias,
                      const float* __restrict__ bias16,
                      float* __restrict__ ua, float* __restrict__ ub,
                      float* __restrict__ kb0, float* __restrict__ kb1,
                      float* __restrict__ qb1, float* __restrict__ qb0, int nrows) {
  const int side = blockIdx.y;
  const float* x  = side ? xb : xa;
  const int* idx  = side ? idxb : idxa;
  const __half* Wtp = Wt2 + (size_t)side * 144 * 128;
  const float* bp = bias + side * HF;
  const float* b8 = bias16 + side * 16;
  float* uout = side ? ub : ua;
  float* kout = side ? kb1 : kb0;
  float* qout = side ? qb0 : qb1;

  __shared__ __align__(16) unsigned short sm[26624];
  char* Asm = (char*)sm;
  char* Wsm = (char*)(sm + 8192);
  const int tid = threadIdx.x;
  const int w = tid >> 6, lane = tid & 63;
  const int row0 = blockIdx.x * 64;

  #pragma unroll
  for (int p = 0; p < 9; ++p) {
    int i = p * 256 + tid;
    int col = i >> 4, kp = i & 15;
    float4 v = *(const float4*)(Wtp + col * 128 + kp * 8);
    int dst = (col * 256 + kp * 16) ^ ((col & 7) << 4);
    *(float4*)(Wsm + dst) = v;
  }
  {
    int r = tid >> 2;
    int rr = row0 + r;
    int g = (rr < nrows) ? (idx ? idx[rr] : rr) : 0;
    const float* xp = x + (size_t)g * 128 + (tid & 3) * 8;
    #pragma unroll
    for (int p = 0; p < 4; ++p) {
      float4 v0 = *(const float4*)(xp + p * 32);
      float4 v1 = *(const float4*)(xp + p * 32 + 4);
      uint4 o;
      o.x = pkh2(v0.x, v0.y); o.y = pkh2(v0.z, v0.w);
      o.z = pkh2(v1.x, v1.y); o.w = pkh2(v1.z, v1.w);
      int k0 = (tid & 3) * 8 + p * 32;
      int dst = (r * 256 + k0 * 2) ^ ((r & 7) << 4);
      *(uint4*)(Asm + dst) = o;
    }
  }
  __syncthreads();

  floatx4 acc[9];
  #pragma unroll
  for (int t = 0; t < 8; ++t) {
    float b = bp[t * 16 + (lane & 15)];
    acc[t] = (floatx4){b, b, b, b};
  }
  {
    float b = b8[lane & 15];
    acc[8] = (floatx4){b, b, b, b};
  }

  const int lrow = lane & 15, lk = lane >> 4;
  #pragma unroll
  for (int kb = 0; kb < 4; ++kb) {
    int r = w * 16 + lrow;
    int abyte = (r * 256 + kb * 64 + lk * 16) ^ ((r & 7) << 4);
    half8 af = *(const half8*)(Asm + abyte);
    #pragma unroll
    for (int t = 0; t < 9; ++t) {
      int c = t * 16 + lrow;
      int bbyte = (c * 256 + kb * 64 + lk * 16) ^ ((c & 7) << 4);
      half8 bf = *(const half8*)(Wsm + bbyte);
      acc[t] = __builtin_amdgcn_mfma_f32_16x16x32_f16(af, bf, acc[t], 0, 0, 0);
    }
  }

  unsigned short* up = (unsigned short*)uout;
  #pragma unroll
  for (int j = 0; j < 4; ++j) {
    int rr = row0 + w * 16 + (lane >> 4) * 4 + j;
    if (rr < nrows) {
      #pragma unroll
      for (int t = 0; t < 8; ++t) {
        __half h = __float2half(acc[t][j]);
        up[(size_t)rr * 128 + t * 16 + (lane & 15)] = *(unsigned short*)&h;
      }
      int col = lane & 15;
      if (col < 8) kout[(size_t)rr * 8 + col] = acc[8][j];
      else         qout[(size_t)rr * 8 + (col - 8)] = acc[8][j];
    }
  }
}

// ================= fold Wf = Wv @ Wqk [Kx,8], bias bf = bv@Wqk + bqk =================
__global__ __launch_bounds__(256)
void fold_kernel(const float* __restrict__ l1_Wv, const float* __restrict__ l1_bv,
                 const float* __restrict__ l1_Wq, const float* __restrict__ l1_bq,
                 const float* __restrict__ l1_Wk, const float* __restrict__ l1_bk,
                 const float* __restrict__ l2_Wv, const float* __restrict__ l2_bv,
                 const float* __restrict__ l2_Wq, const float* __restrict__ l2_bq,
                 const float* __restrict__ l2_Wk, const float* __restrict__ l2_bk,
                 float* __restrict__ outbuf) {
  int b = blockIdx.x;
  int layer = b >> 2, rel = (b >> 1) & 1, qk = b & 1;
  int Kx = (layer == 0) ? 128 : 16;
  const float* Wv = ((layer == 0) ? l1_Wv : l2_Wv) + (size_t)rel * Kx * HF;
  const float* bv = ((layer == 0) ? l1_bv : l2_bv) + rel * HF;
  const float* Wqk = ((layer == 0) ? (qk ? l1_Wk : l1_Wq) : (qk ? l2_Wk : l2_Wq)) + (size_t)rel * HF * 8;
  const float* bqk = ((layer == 0) ? (qk ? l1_bk : l1_bq) : (qk ? l2_bk : l2_bq)) + rel * 8;
  float* o = outbuf + (size_t)b * 1040;
  for (int t = threadIdx.x; t < Kx * 8; t += 256) {
    int row = t >> 3, c = t & 7;
    float acc = 0.f;
    for (int j = 0; j < HF; ++j) acc += Wv[row * HF + j] * Wqk[j * 8 + c];
    o[t] = acc;
  }
  for (int t = threadIdx.x; t < 8; t += 256) {
    float acc = bqk[t];
    for (int j = 0; j < HF; ++j) acc += bv[j] * Wqk[j * 8 + t];
    o[Kx * 8 + t] = acc;
  }
}

// ========== L2 qk: k2 = x@Wfk, q = x@Wfq ([n,16] -> [n,8] each) ; grid (nb,2) ==========
__global__ __launch_bounds__(256)
void qk16_kernel(const float* __restrict__ xA, const float* __restrict__ xB,
                 const float* __restrict__ WfkA, const float* __restrict__ WfqA,
                 const float* __restrict__ WfkB, const float* __restrict__ WfqB,
                 float* __restrict__ k2a, float* __restrict__ k2b,
                 float* __restrict__ qA, float* __restrict__ qB, int n) {
  const int side = blockIdx.y;
  const float* x   = side ? xB : xA;
  const float* Wfk = side ? WfkB : WfkA;
  const float* Wfq = side ? WfqB : WfqA;
  float* k2  = side ? k2b : k2a;
  float* qout = side ? qB : qA;
  __shared__ float Wk[136], Wq[136];
  const int tid = threadIdx.x;
  for (int i = tid; i < 136; i += 256) { Wk[i] = Wfk[i]; Wq[i] = Wfq[i]; }
  __syncthreads();
  int row = blockIdx.x * 32 + (tid >> 3), col = tid & 7;
  if (row >= n) return;
  const float* xr = x + (size_t)row * 16;
  float ak = Wk[128 + col], aq = Wq[128 + col];
  #pragma unroll
  for (int j4 = 0; j4 < 4; ++j4) {
    float4 v = *(const float4*)(xr + j4 * 4);
    float xv[4] = {v.x, v.y, v.z, v.w};
    #pragma unroll
    for (int j = 0; j < 4; ++j) {
      ak += xv[j] * Wk[(j4 * 4 + j) * 8 + col];
      aq += xv[j] * Wq[(j4 * 4 + j) * 8 + col];
    }
  }
  k2[row * 8 + col] = ak;
  qout[row * 8 + col] = aq;
}

// ================= batched CSR build (both relations at once) =================
__global__ __launch_bounds__(256)
void hist2_kernel(const int* __restrict__ dst0, const int* __restrict__ dst1,
                  int* __restrict__ cnt) {
  int e = blockIdx.x * 256 + threadIdx.x;
  if (e < NEDGE) atomicAdd(&cnt[dst0[e]], 1);
  else if (e < 2 * NEDGE) atomicAdd(&cnt[N_NODES + dst1[e - NEDGE]], 1);
}

__global__ __launch_bounds__(256)
void scan_bsum_kernel(const int* __restrict__ cnt, int* __restrict__ bsum, int n) {
  __shared__ int s[256];
  int i = blockIdx.x * 256 + threadIdx.x;
  s[threadIdx.x] = (i < n) ? cnt[i] : 0;
  __syncthreads();
  for (int o = 128; o > 0; o >>= 1) {
    if (threadIdx.x < o) s[threadIdx.x] += s[threadIdx.x + o];
    __syncthreads();
  }
  if (threadIdx.x == 0) bsum[blockIdx.x] = s[0];
}

__global__ __launch_bounds__(512)
void scan_offsets_kernel(int* __restrict__ bsum, int nb) {
  __shared__ int s[512];
  int t = threadIdx.x;
  s[t] = (t < nb) ? bsum[t] : 0;
  __syncthreads();
  for (int o = 1; o < 512; o <<= 1) {
    int v = (t >= o) ? s[t - o] : 0;
    __syncthreads();
    s[t] += v;
    __syncthreads();
  }
  if (t < nb) bsum[t] = (t == 0) ? 0 : s[t - 1];
}

__global__ __launch_bounds__(256)
void scan_final_kernel(const int* __restrict__ cnt, const int* __restrict__ boff,
                       int* __restrict__ row_start, int n) {
  __shared__ int s[256];
  int t = threadIdx.x, i = blockIdx.x * 256 + t;
  int v = (i < n) ? cnt[i] : 0;
  s[t] = v;
  __syncthreads();
  for (int o = 1; o < 256; o <<= 1) {
    int w = (t >= o) ? s[t - o] : 0;
    __syncthreads();
    s[t] += w;
    __syncthreads();
  }
  if (i < n)  row_start[i] = boff[blockIdx.x] + s[t] - v;
  if (i == n - 1) row_start[n] = boff[blockIdx.x] + s[t];
}

__global__ __launch_bounds__(256)
void csr_scatter2_kernel(const int* __restrict__ s0, const int* __restrict__ d0,
                         const int* __restrict__ s1, const int* __restrict__ d1,
                         const int* __restrict__ rs, int* __restrict__ fill,
                         int* __restrict__ cs) {
  int e = blockIdx.x * 256 + threadIdx.x;
  if (e >= 2 * NEDGE) return;
  int rel = (e >= NEDGE);
  int ee = rel ? e - NEDGE : e;
  int d = rel ? d1[ee] : d0[ee];
  int s = rel ? s1[ee] : s0[ee];
  int key = rel * N_NODES + d;
  int pos = rs[key] + atomicAdd(&fill[key], 1);
  cs[pos] = s;
}

// ========= L1 GAT aggregation, 32 lanes/node, fp16 u, fp32 k; MASKED 8-batches =========
// All edges processed in 8-deep batches (last batch clamps indices, masks ex=0).
// The old serial tail ran ~4 dependent ~900cy HBM gather chains per node (22% of
// Poisson(10) nodes were ENTIRELY serial) - now every edge's loads issue 8-wide.
__global__ __launch_bounds__(256)
void node_agg2_kernel(const int* __restrict__ rs, const int* __restrict__ cs,
                      const float* __restrict__ u0, const float* __restrict__ u1,
                      const float* __restrict__ kb0, const float* __restrict__ kb1,
                      const float* __restrict__ qt0, const float* __restrict__ qt1,
                      float* __restrict__ out0, float* __restrict__ out1, int elu) {
  int grp  = (blockIdx.x * 256 + threadIdx.x) >> 5;
  int lane = threadIdx.x & 31;
  if (grp >= 2 * N_NODES) return;
  int rel = grp >= N_NODES;
  int node = grp - (rel ? N_NODES : 0);
  const float* ut = rel ? u1 : u0;
  const float* kb = rel ? kb1 : kb0;
  const float* qt = rel ? qt1 : qt0;
  float* out      = rel ? out1 : out0;

  int e0 = rs[grp], e1 = rs[grp + 1];
  const int hd = lane >> 2;
  float qh = qt[node * 8 + hd];
  float den = 0.f;
  float4 acc = make_float4(0.f, 0.f, 0.f, 0.f);

  for (int e = e0; e < e1; e += 8) {
    int m = e1 - e;                      // >= 1
    int s[8];
    #pragma unroll
    for (int j = 0; j < 8; ++j) s[j] = cs[e + (j < m ? j : m - 1)];
    uint2 uv[8]; float kv[8];
    #pragma unroll
    for (int j = 0; j < 8; ++j) {
      uv[j] = *(const uint2*)((const char*)(ut + (size_t)s[j] * UST) + lane * 8);
      kv[j] = kb[s[j] * 8 + hd];
    }
    #pragma unroll
    for (int j = 0; j < 8; ++j) {
      float sc = kv[j] + qh; sc = sc > 0.f ? sc : 0.2f * sc;
      float ex = (j < m) ? __expf(sc) : 0.f;
      den += ex;
      float2 f01 = __half22float2(*(__half2*)&uv[j].x);
      float2 f23 = __half22float2(*(__half2*)&uv[j].y);
      acc.x += ex * f01.x; acc.y += ex * f01.y;
      acc.z += ex * f23.x; acc.w += ex * f23.y;
    }
  }
  float inv = den > 0.f ? 1.f / den : 0.f;
  float4 r = make_float4(acc.x * inv, acc.y * inv, acc.z * inv, acc.w * inv);
  #pragma unroll
  for (int m2 = 4; m2 <= 16; m2 <<= 1) {
    r.x += __shfl_xor(r.x, m2); r.y += __shfl_xor(r.y, m2);
    r.z += __shfl_xor(r.z, m2); r.w += __shfl_xor(r.w, m2);
  }
  r.x *= 0.125f; r.y *= 0.125f; r.z *= 0.125f; r.w *= 0.125f;
  if (elu) {
    r.x = r.x > 0.f ? r.x : expm1f(r.x);
    r.y = r.y > 0.f ? r.y : expm1f(r.y);
    r.z = r.z > 0.f ? r.z : expm1f(r.z);
    r.w = r.w > 0.f ? r.w : expm1f(r.w);
  }
  if (lane < 4) *(float4*)&out[(size_t)node * FEAT + lane * 4] = r;
}

// ========= L2 GAT aggregation via z-trick, rel-split grid; MASKED 8-batches =========
__global__ __launch_bounds__(256)
void agg_l2z_kernel(const int* __restrict__ rs, const int* __restrict__ cs,
                    const float* __restrict__ xA, const float* __restrict__ xB,
                    const float* __restrict__ k2a, const float* __restrict__ k2b,
                    const float* __restrict__ qt0, const float* __restrict__ qt1,
                    const float* __restrict__ Wv, const float* __restrict__ bv,
                    float* __restrict__ out) {
  const int rel = blockIdx.y;
  __shared__ float Wt_lds[128 * 16];
  __shared__ float z_lds[8][128];
  __shared__ float bvs[16];
  const int tid = threadIdx.x;
  for (int i = tid; i < 2048; i += 256) {
    int j = i >> 7, c = i & 127, h = c >> 4, o = c & 15;
    Wt_lds[(h * 16 + j) * 16 + o] = Wv[rel * 2048 + i];
  }
  if (tid < 16) {
    float s = 0.f;
    #pragma unroll
    for (int h = 0; h < 8; ++h) s += bv[rel * 128 + h * 16 + tid];
    bvs[tid] = s;
  }
  __syncthreads();

  int node = blockIdx.x * 8 + (tid >> 5);
  int lane = tid & 31;
  int gl   = tid >> 5;
  const float* x  = rel ? xB : xA;
  const float* k2 = rel ? k2b : k2a;
  const float* qt = rel ? qt1 : qt0;
  int grp = rel * N_NODES + node;

  int e0 = rs[grp], e1 = rs[grp + 1];
  const int h = lane >> 2, jg = (lane & 3) * 4;
  float qh = qt[node * 8 + h];
  float den = 0.f;
  float4 z = make_float4(0.f, 0.f, 0.f, 0.f);

  for (int e = e0; e < e1; e += 8) {
    int m = e1 - e;
    int s[8];
    #pragma unroll
    for (int j = 0; j < 8; ++j) s[j] = cs[e + (j < m ? j : m - 1)];
    float kv[8]; float4 xv[8];
    #pragma unroll
    for (int j = 0; j < 8; ++j) {
      kv[j] = k2[s[j] * 8 + h];
      xv[j] = *(const float4*)&x[(size_t)s[j] * 16 + jg];
    }
    #pragma unroll
    for (int j = 0; j < 8; ++j) {
      float sc = kv[j] + qh; sc = sc > 0.f ? sc : 0.2f * sc;
      float ex = (j < m) ? __expf(sc) : 0.f;
      den += ex;
      z.x += ex * xv[j].x; z.y += ex * xv[j].y;
      z.z += ex * xv[j].z; z.w += ex * xv[j].w;
    }
  }
  float inv = den > 0.f ? 1.f / den : 0.f;
  z.x *= inv; z.y *= inv; z.z *= inv; z.w *= inv;
  *(float4*)&z_lds[gl][h * 16 + jg] = z;
  // no barrier: z_lds[gl] write+read are wave-local

  const int o = lane & 15, half = lane >> 4;
  float acc = 0.f;
  #pragma unroll
  for (int hg = 0; hg < 4; ++hg) {
    int h2 = half * 4 + hg;
    const float* zr = &z_lds[gl][h2 * 16];
    float4 z0 = *(const float4*)zr;
    float4 z1 = *(const float4*)(zr + 4);
    float4 z2 = *(const float4*)(zr + 8);
    float4 z3 = *(const float4*)(zr + 12);
    const float* wb = &Wt_lds[h2 * 256 + o];
    acc += z0.x * wb[0]   + z0.y * wb[16]  + z0.z * wb[32]  + z0.w * wb[48]
         + z1.x * wb[64]  + z1.y * wb[80]  + z1.z * wb[96]  + z1.w * wb[112]
         + z2.x * wb[128] + z2.y * wb[144] + z2.z * wb[160] + z2.w * wb[176]
         + z3.x * wb[192] + z3.y * wb[208] + z3.z * wb[224] + z3.w * wb[240];
  }
  acc += __shfl_xor(acc, 16);
  if (lane < 16) {
    float r = 0.125f * (acc + ((e1 > e0) ? bvs[o] : 0.f));
    float* ob = out + (rel ? 0 : (size_t)N_NODES * FEAT);
    ob[(size_t)node * FEAT + o] = r;
  }
}

extern "C" void kernel_launch(void* const* d_in, const int* in_sizes, int n_in,
                              void* d_out, int out_size, void* d_ws, size_t ws_size,
                              hipStream_t stream) {
  const int* idx_a  = (const int*)d_in[0];
  const int* idx_b  = (const int*)d_in[1];
  const int* src_r0 = (const int*)d_in[2];
  const int* dst_r0 = (const int*)d_in[3];
  const int* src_r1 = (const int*)d_in[4];
  const int* dst_r1 = (const int*)d_in[5];
  const float* emb_a = (const float*)d_in[6];
  const float* emb_b = (const float*)d_in[7];
  const float* l1_Wv = (const float*)d_in[8];
  const float* l1_bv = (const float*)d_in[9];
  const float* l1_Wq = (const float*)d_in[10];
  const float* l1_bq = (const float*)d_in[11];
  const float* l1_Wk = (const float*)d_in[12];
  const float* l1_bk = (const float*)d_in[13];
  const float* l2_Wv = (const float*)d_in[14];
  const float* l2_bv = (const float*)d_in[15];
  const float* l2_Wq = (const float*)d_in[16];
  const float* l2_bq = (const float*)d_in[17];
  const float* l2_Wk = (const float*)d_in[18];
  const float* l2_bk = (const float*)d_in[19];
  float* out = (float*)d_out;

  char* ws = (char*)d_ws;
  size_t off = 0;
  auto alloc = [&](size_t bytes) {
    void* p = ws + off; off += (bytes + 255) & ~255ULL; return p;
  };
  float*  u0    = (float*)alloc((size_t)N_NODES * UST * 4);
  float*  u1    = (float*)alloc((size_t)N_NODES * UST * 4);
  __half* Wt2   = (__half*)alloc(2 * 144 * 128 * 2);
  float*  b16   = (float*)alloc(2 * 16 * 4);
  float*  kb0   = (float*)alloc((size_t)N_NODES * HEADS * 4);
  float*  kb1   = (float*)alloc((size_t)N_NODES * HEADS * 4);
  float*  qb0   = (float*)alloc((size_t)N_NODES * HEADS * 4);
  float*  qb1   = (float*)alloc((size_t)N_NODES * HEADS * 4);
  float*  k2a   = (float*)alloc((size_t)N_NODES * HEADS * 4);
  float*  k2b   = (float*)alloc((size_t)N_NODES * HEADS * 4);
  float*  xA    = (float*)alloc((size_t)N_NODES * FEAT * 4);
  float*  xB    = (float*)alloc((size_t)N_NODES * FEAT * 4);
  int*    rs    = (int*)  alloc((size_t)(2 * N_NODES + 1) * 4);
  int*    cs    = (int*)  alloc((size_t)2 * NEDGE * 4);
  int*    cnt   = (int*)  alloc((size_t)4 * N_NODES * 4);
  int*    bsum  = (int*)  alloc(512 * 4);
  float*  wf    = (float*)alloc(8 * 1040 * 4);

  dim3 blk(256);
  const int n2 = 2 * N_NODES;
  int* fill = cnt + n2;
  const int nScanBlk  = (n2 + 255) / 256;
  const int nEdgeBlk2 = (2 * NEDGE + 255) / 256;
  const int nAggBlk   = (n2 + 7) / 8;
  const int nAggL2    = N_NODES / 8;
  const int nGemmBlk64 = (N_NODES + 63) / 64;
  const int nQk16Blk   = (N_NODES + 31) / 32;

  fold_kernel<<<8, blk, 0, stream>>>(l1_Wv, l1_bv, l1_Wq, l1_bq, l1_Wk, l1_bk,
                                     l2_Wv, l2_bv, l2_Wq, l2_bq, l2_Wk, l2_bk, wf);
  prep_wt2_kernel<<<2, blk, 0, stream>>>(l1_Wv, wf, Wt2, b16);
  auto wslot = [&](int layer, int rel, int qk) {
    return wf + (size_t)((layer << 2) | (rel << 1) | qk) * 1040;
  };

  hipMemsetAsync(cnt, 0, (size_t)2 * n2 * 4, stream);
  hist2_kernel<<<nEdgeBlk2, blk, 0, stream>>>(dst_r0, dst_r1, cnt);
  scan_bsum_kernel<<<nScanBlk, blk, 0, stream>>>(cnt, bsum, n2);
  scan_offsets_kernel<<<1, dim3(512), 0, stream>>>(bsum, nScanBlk);
  scan_final_kernel<<<nScanBlk, blk, 0, stream>>>(cnt, bsum, rs, n2);
  csr_scatter2_kernel<<<nEdgeBlk2, blk, 0, stream>>>(src_r0, dst_r0, src_r1, dst_r1,
                                                     rs, fill, cs);

  // ---- layer 1 (u + k + q all from one MFMA kernel) ----
  {
    gemm_mfma_kernel<<<dim3(nGemmBlk64, 2), blk, 0, stream>>>(
        emb_a, idx_a, emb_b, idx_b, Wt2, l1_bv, b16,
        u0, u1, kb0, kb1, qb1, qb0, N_NODES);
    node_agg2_kernel<<<nAggBlk, blk, 0, stream>>>(rs, cs, u0, u1, kb0, kb1,
                                                  qb0, qb1, xB, xA, 1);
  }
  // ---- layer 2 (z-trick, rel-split grid) ----
  {
    qk16_kernel<<<dim3(nQk16Blk, 2), blk, 0, stream>>>(
        xA, xB,
        wslot(1,0,1), wslot(1,1,0), wslot(1,1,1), wslot(1,0,0),
        k2a, k2b, qb1, qb0, N_NODES);
    agg_l2z_kernel<<<dim3(nAggL2, 2), blk, 0, stream>>>(
        rs, cs, xA, xB, k2a, k2b, qb0, qb1, l2_Wv, l2_bv, out);
  }
}

// Round 23
// 265.430 us; speedup vs baseline: 1.1718x; 1.0126x over previous
//
#include <hip/hip_runtime.h>
#include <hip/hip_fp16.h>

#define N_NODES 50000
#define NEDGE   500000
#define HEADS   8
#define FEAT    16
#define HF      128   // HEADS*FEAT
#define UST     64    // u row stride in FLOATS: 128 fp16 = 256B
#define XKST    32    // xk row stride in HALVES: 16 fp16 x | 8 fp16 k2 | 8 pad = 64B

typedef __attribute__((ext_vector_type(8))) _Float16 half8;
typedef __attribute__((ext_vector_type(4))) float floatx4;

__device__ __forceinline__ unsigned pkh2(float a, float b) {
  __half2 h = __floats2half2_rn(a, b);
  return *(unsigned*)&h;
}

// ===== prep: Wt2[side][col][k] fp16, col 0-127 = Wv, 128-135 = Wfk, 136-143 = Wfq
__global__ __launch_bounds__(256)
void prep_wt2_kernel(const float* __restrict__ W, const float* __restrict__ wf,
                     __half* __restrict__ Wt2, float* __restrict__ bias16) {
  int side = blockIdx.x;
  const float* Wp  = W + (size_t)side * 16384;
  const float* wfk = wf + (size_t)(side == 0 ? 1 : 3) * 1040;
  const float* wfq = wf + (size_t)(side == 0 ? 2 : 0) * 1040;
  __half* o = Wt2 + (size_t)side * 144 * 128;
  for (int j = threadIdx.x; j < 144 * 128; j += 256) {
    int col = j >> 7, k = j & 127;
    float v = (col < 128) ? Wp[k * 128 + col]
            : (col < 136) ? wfk[k * 8 + (col - 128)]
                          : wfq[k * 8 + (col - 136)];
    o[j] = __float2half(v);
  }
  if (threadIdx.x < 16) {
    int c = threadIdx.x;
    bias16[side * 16 + c] = (c < 8) ? wfk[1024 + c] : wfq[1024 + (c - 8)];
  }
}

// ========== MFMA GEMM + fused qk: u(fp16), k(fp32), q(fp32) ; grid (782, 2) ==========
__global__ __launch_bounds__(256)
void gemm_mfma_kernel(const float* __restrict__ xa, const int* __restrict__ idxa,
                      const float* __restrict__ xb, const int* __restrict__ idxb,
                      const __half* __restrict__ Wt2, const float* __restrict__ bias,
                      const float* __restrict__ bias16,
                      float* __restrict__ ua, float* __restrict__ ub,
                      float* __restrict__ kb0, float* __restrict__ kb1,
                      float* __restrict__ qb1, float* __restrict__ qb0, int nrows) {
  const int side = blockIdx.y;
  const float* x  = side ? xb : xa;
  const int* idx  = side ? idxb : idxa;
  const __half* Wtp = Wt2 + (size_t)side * 144 * 128;
  const float* bp = bias + side * HF;
  const float* b8 = bias16 + side * 16;
  float* uout = side ? ub : ua;
  float* kout = side ? kb1 : kb0;
  float* qout = side ? qb0 : qb1;

  __shared__ __align__(16) unsigned short sm[26624];
  char* Asm = (char*)sm;
  char* Wsm = (char*)(sm + 8192);
  const int tid = threadIdx.x;
  const int w = tid >> 6, lane = tid & 63;
  const int row0 = blockIdx.x * 64;

  #pragma unroll
  for (int p = 0; p < 9; ++p) {
    int i = p * 256 + tid;
    int col = i >> 4, kp = i & 15;
    float4 v = *(const float4*)(Wtp + col * 128 + kp * 8);
    int dst = (col * 256 + kp * 16) ^ ((col & 7) << 4);
    *(float4*)(Wsm + dst) = v;
  }
  {
    int r = tid >> 2;
    int rr = row0 + r;
    int g = (rr < nrows) ? (idx ? idx[rr] : rr) : 0;
    const float* xp = x + (size_t)g * 128 + (tid & 3) * 8;
    #pragma unroll
    for (int p = 0; p < 4; ++p) {
      float4 v0 = *(const float4*)(xp + p * 32);
      float4 v1 = *(const float4*)(xp + p * 32 + 4);
      uint4 o;
      o.x = pkh2(v0.x, v0.y); o.y = pkh2(v0.z, v0.w);
      o.z = pkh2(v1.x, v1.y); o.w = pkh2(v1.z, v1.w);
      int k0 = (tid & 3) * 8 + p * 32;
      int dst = (r * 256 + k0 * 2) ^ ((r & 7) << 4);
      *(uint4*)(Asm + dst) = o;
    }
  }
  __syncthreads();

  floatx4 acc[9];
  #pragma unroll
  for (int t = 0; t < 8; ++t) {
    float b = bp[t * 16 + (lane & 15)];
    acc[t] = (floatx4){b, b, b, b};
  }
  {
    float b = b8[lane & 15];
    acc[8] = (floatx4){b, b, b, b};
  }

  const int lrow = lane & 15, lk = lane >> 4;
  #pragma unroll
  for (int kb = 0; kb < 4; ++kb) {
    int r = w * 16 + lrow;
    int abyte = (r * 256 + kb * 64 + lk * 16) ^ ((r & 7) << 4);
    half8 af = *(const half8*)(Asm + abyte);
    #pragma unroll
    for (int t = 0; t < 9; ++t) {
      int c = t * 16 + lrow;
      int bbyte = (c * 256 + kb * 64 + lk * 16) ^ ((c & 7) << 4);
      half8 bf = *(const half8*)(Wsm + bbyte);
      acc[t] = __builtin_amdgcn_mfma_f32_16x16x32_f16(af, bf, acc[t], 0, 0, 0);
    }
  }

  unsigned short* up = (unsigned short*)uout;
  #pragma unroll
  for (int j = 0; j < 4; ++j) {
    int rr = row0 + w * 16 + (lane >> 4) * 4 + j;
    if (rr < nrows) {
      #pragma unroll
      for (int t = 0; t < 8; ++t) {
        __half h = __float2half(acc[t][j]);
        up[(size_t)rr * 128 + t * 16 + (lane & 15)] = *(unsigned short*)&h;
      }
      int col = lane & 15;
      if (col < 8) kout[(size_t)rr * 8 + col] = acc[8][j];
      else         qout[(size_t)rr * 8 + (col - 8)] = acc[8][j];
    }
  }
}

// ================= fold Wf = Wv @ Wqk [Kx,8], bias bf = bv@Wqk + bqk =================
__global__ __launch_bounds__(256)
void fold_kernel(const float* __restrict__ l1_Wv, const float* __restrict__ l1_bv,
                 const float* __restrict__ l1_Wq, const float* __restrict__ l1_bq,
                 const float* __restrict__ l1_Wk, const float* __restrict__ l1_bk,
                 const float* __restrict__ l2_Wv, const float* __restrict__ l2_bv,
                 const float* __restrict__ l2_Wq, const float* __restrict__ l2_bq,
                 const float* __restrict__ l2_Wk, const float* __restrict__ l2_bk,
                 float* __restrict__ outbuf) {
  int b = blockIdx.x;
  int layer = b >> 2, rel = (b >> 1) & 1, qk = b & 1;
  int Kx = (layer == 0) ? 128 : 16;
  const float* Wv = ((layer == 0) ? l1_Wv : l2_Wv) + (size_t)rel * Kx * HF;
  const float* bv = ((layer == 0) ? l1_bv : l2_bv) + rel * HF;
  const float* Wqk = ((layer == 0) ? (qk ? l1_Wk : l1_Wq) : (qk ? l2_Wk : l2_Wq)) + (size_t)rel * HF * 8;
  const float* bqk = ((layer == 0) ? (qk ? l1_bk : l1_bq) : (qk ? l2_bk : l2_bq)) + rel * 8;
  float* o = outbuf + (size_t)b * 1040;
  for (int t = threadIdx.x; t < Kx * 8; t += 256) {
    int row = t >> 3, c = t & 7;
    float acc = 0.f;
    for (int j = 0; j < HF; ++j) acc += Wv[row * HF + j] * Wqk[j * 8 + c];
    o[t] = acc;
  }
  for (int t = threadIdx.x; t < 8; t += 256) {
    float acc = bqk[t];
    for (int j = 0; j < HF; ++j) acc += bv[j] * Wqk[j * 8 + t];
    o[Kx * 8 + t] = acc;
  }
}

// ========== L2 qk on packed fp16 xk rows: k2 -> xk[16:24) fp16, q -> qout fp32 ==========
__global__ __launch_bounds__(256)
void qk16_kernel(__half* __restrict__ xk_a, __half* __restrict__ xk_b,
                 const float* __restrict__ WfkA, const float* __restrict__ WfqA,
                 const float* __restrict__ WfkB, const float* __restrict__ WfqB,
                 float* __restrict__ qA, float* __restrict__ qB, int n) {
  const int side = blockIdx.y;
  __half* xk = side ? xk_b : xk_a;
  const float* Wfk = side ? WfkB : WfkA;
  const float* Wfq = side ? WfqB : WfqA;
  float* qout = side ? qB : qA;
  __shared__ float Wk[136], Wq[136];
  const int tid = threadIdx.x;
  for (int i = tid; i < 136; i += 256) { Wk[i] = Wfk[i]; Wq[i] = Wfq[i]; }
  __syncthreads();
  int row = blockIdx.x * 32 + (tid >> 3), col = tid & 7;
  if (row >= n) return;
  const __half* xr = xk + (size_t)row * XKST;
  uint4 p0 = *(const uint4*)xr;            // fp16 x[0..7]
  uint4 p1 = *(const uint4*)(xr + 8);      // fp16 x[8..15]
  float xv[16];
  {
    unsigned pp[8] = {p0.x, p0.y, p0.z, p0.w, p1.x, p1.y, p1.z, p1.w};
    #pragma unroll
    for (int j = 0; j < 8; ++j) {
      float2 f = __half22float2(*(__half2*)&pp[j]);
      xv[j * 2] = f.x; xv[j * 2 + 1] = f.y;
    }
  }
  float ak = Wk[128 + col], aq = Wq[128 + col];
  #pragma unroll
  for (int j = 0; j < 16; ++j) {
    ak += xv[j] * Wk[j * 8 + col];
    aq += xv[j] * Wq[j * 8 + col];
  }
  xk[(size_t)row * XKST + 16 + col] = __float2half(ak);   // own row, disjoint half
  qout[row * 8 + col] = aq;
}

// ================= batched CSR build (both relations at once) =================
__global__ __launch_bounds__(256)
void hist2_kernel(const int* __restrict__ dst0, const int* __restrict__ dst1,
                  int* __restrict__ cnt) {
  int e = blockIdx.x * 256 + threadIdx.x;
  if (e < NEDGE) atomicAdd(&cnt[dst0[e]], 1);
  else if (e < 2 * NEDGE) atomicAdd(&cnt[N_NODES + dst1[e - NEDGE]], 1);
}

__global__ __launch_bounds__(256)
void scan_bsum_kernel(const int* __restrict__ cnt, int* __restrict__ bsum, int n) {
  __shared__ int s[256];
  int i = blockIdx.x * 256 + threadIdx.x;
  s[threadIdx.x] = (i < n) ? cnt[i] : 0;
  __syncthreads();
  for (int o = 128; o > 0; o >>= 1) {
    if (threadIdx.x < o) s[threadIdx.x] += s[threadIdx.x + o];
    __syncthreads();
  }
  if (threadIdx.x == 0) bsum[blockIdx.x] = s[0];
}

__global__ __launch_bounds__(512)
void scan_offsets_kernel(int* __restrict__ bsum, int nb) {
  __shared__ int s[512];
  int t = threadIdx.x;
  s[t] = (t < nb) ? bsum[t] : 0;
  __syncthreads();
  for (int o = 1; o < 512; o <<= 1) {
    int v = (t >= o) ? s[t - o] : 0;
    __syncthreads();
    s[t] += v;
    __syncthreads();
  }
  if (t < nb) bsum[t] = (t == 0) ? 0 : s[t - 1];
}

__global__ __launch_bounds__(256)
void scan_final_kernel(const int* __restrict__ cnt, const int* __restrict__ boff,
                       int* __restrict__ row_start, int n) {
  __shared__ int s[256];
  int t = threadIdx.x, i = blockIdx.x * 256 + t;
  int v = (i < n) ? cnt[i] : 0;
  s[t] = v;
  __syncthreads();
  for (int o = 1; o < 256; o <<= 1) {
    int w = (t >= o) ? s[t - o] : 0;
    __syncthreads();
    s[t] += w;
    __syncthreads();
  }
  if (i < n)  row_start[i] = boff[blockIdx.x] + s[t] - v;
  if (i == n - 1) row_start[n] = boff[blockIdx.x] + s[t];
}

__global__ __launch_bounds__(256)
void csr_scatter2_kernel(const int* __restrict__ s0, const int* __restrict__ d0,
                         const int* __restrict__ s1, const int* __restrict__ d1,
                         const int* __restrict__ rs, int* __restrict__ fill,
                         int* __restrict__ cs) {
  int e = blockIdx.x * 256 + threadIdx.x;
  if (e >= 2 * NEDGE) return;
  int rel = (e >= NEDGE);
  int ee = rel ? e - NEDGE : e;
  int d = rel ? d1[ee] : d0[ee];
  int s = rel ? s1[ee] : s0[ee];
  int key = rel * N_NODES + d;
  int pos = rs[key] + atomicAdd(&fill[key], 1);
  cs[pos] = s;
}

// ========= L1 GAT aggregation, 32 lanes/node, fp16 u, fp32 k; MASKED 8-batches =========
// Output x written as fp16 into packed xk rows (feeds qk16 + agg_l2z).
__global__ __launch_bounds__(256)
void node_agg2_kernel(const int* __restrict__ rs, const int* __restrict__ cs,
                      const float* __restrict__ u0, const float* __restrict__ u1,
                      const float* __restrict__ kb0, const float* __restrict__ kb1,
                      const float* __restrict__ qt0, const float* __restrict__ qt1,
                      __half* __restrict__ out0, __half* __restrict__ out1) {
  int grp  = (blockIdx.x * 256 + threadIdx.x) >> 5;
  int lane = threadIdx.x & 31;
  if (grp >= 2 * N_NODES) return;
  int rel = grp >= N_NODES;
  int node = grp - (rel ? N_NODES : 0);
  const float* ut = rel ? u1 : u0;
  const float* kb = rel ? kb1 : kb0;
  const float* qt = rel ? qt1 : qt0;
  __half* out     = rel ? out1 : out0;

  int e0 = rs[grp], e1 = rs[grp + 1];
  const int hd = lane >> 2;
  float qh = qt[node * 8 + hd];
  float den = 0.f;
  float4 acc = make_float4(0.f, 0.f, 0.f, 0.f);

  for (int e = e0; e < e1; e += 8) {
    int m = e1 - e;
    int s[8];
    #pragma unroll
    for (int j = 0; j < 8; ++j) s[j] = cs[e + (j < m ? j : m - 1)];
    uint2 uv[8]; float kv[8];
    #pragma unroll
    for (int j = 0; j < 8; ++j) {
      uv[j] = *(const uint2*)((const char*)(ut + (size_t)s[j] * UST) + lane * 8);
      kv[j] = kb[s[j] * 8 + hd];
    }
    #pragma unroll
    for (int j = 0; j < 8; ++j) {
      float sc = kv[j] + qh; sc = sc > 0.f ? sc : 0.2f * sc;
      float ex = (j < m) ? __expf(sc) : 0.f;
      den += ex;
      float2 f01 = __half22float2(*(__half2*)&uv[j].x);
      float2 f23 = __half22float2(*(__half2*)&uv[j].y);
      acc.x += ex * f01.x; acc.y += ex * f01.y;
      acc.z += ex * f23.x; acc.w += ex * f23.y;
    }
  }
  float inv = den > 0.f ? 1.f / den : 0.f;
  float4 r = make_float4(acc.x * inv, acc.y * inv, acc.z * inv, acc.w * inv);
  #pragma unroll
  for (int m2 = 4; m2 <= 16; m2 <<= 1) {
    r.x += __shfl_xor(r.x, m2); r.y += __shfl_xor(r.y, m2);
    r.z += __shfl_xor(r.z, m2); r.w += __shfl_xor(r.w, m2);
  }
  r.x *= 0.125f; r.y *= 0.125f; r.z *= 0.125f; r.w *= 0.125f;
  // ELU (always, layer 1)
  r.x = r.x > 0.f ? r.x : expm1f(r.x);
  r.y = r.y > 0.f ? r.y : expm1f(r.y);
  r.z = r.z > 0.f ? r.z : expm1f(r.z);
  r.w = r.w > 0.f ? r.w : expm1f(r.w);
  if (lane < 4) {
    uint2 o;
    o.x = pkh2(r.x, r.y); o.y = pkh2(r.z, r.w);
    *(uint2*)&out[(size_t)node * XKST + lane * 4] = o;   // fp16 x, feats lane*4..+3
  }
}

// ========= L2 GAT aggregation via z-trick on packed xk rows (x + k2 in ONE 64B line) ==
__global__ __launch_bounds__(256)
void agg_l2z_kernel(const int* __restrict__ rs, const int* __restrict__ cs,
                    const __half* __restrict__ xk_a, const __half* __restrict__ xk_b,
                    const float* __restrict__ qt0, const float* __restrict__ qt1,
                    const float* __restrict__ Wv, const float* __restrict__ bv,
                    float* __restrict__ out) {
  const int rel = blockIdx.y;
  __shared__ float Wt_lds[128 * 16];
  __shared__ float z_lds[8][128];
  __shared__ float bvs[16];
  const int tid = threadIdx.x;
  for (int i = tid; i < 2048; i += 256) {
    int j = i >> 7, c = i & 127, h = c >> 4, o = c & 15;
    Wt_lds[(h * 16 + j) * 16 + o] = Wv[rel * 2048 + i];
  }
  if (tid < 16) {
    float s = 0.f;
    #pragma unroll
    for (int h = 0; h < 8; ++h) s += bv[rel * 128 + h * 16 + tid];
    bvs[tid] = s;
  }
  __syncthreads();

  int node = blockIdx.x * 8 + (tid >> 5);
  int lane = tid & 31;
  int gl   = tid >> 5;
  const __half* xk = rel ? xk_b : xk_a;
  const float* qt = rel ? qt1 : qt0;
  int grp = rel * N_NODES + node;

  int e0 = rs[grp], e1 = rs[grp + 1];
  const int h = lane >> 2, fg = lane & 3;
  float qh = qt[node * 8 + h];
  float den = 0.f;
  float4 z = make_float4(0.f, 0.f, 0.f, 0.f);

  for (int e = e0; e < e1; e += 8) {
    int m = e1 - e;
    int s[8];
    #pragma unroll
    for (int j = 0; j < 8; ++j) s[j] = cs[e + (j < m ? j : m - 1)];
    uint2 uv[8]; __half kvh[8];
    #pragma unroll
    for (int j = 0; j < 8; ++j) {
      const __half* p = xk + (size_t)s[j] * XKST;
      uv[j] = *(const uint2*)(p + fg * 4);     // fp16 x feats fg*4..+3
      kvh[j] = p[16 + h];                      // fp16 k2, same 64B line
    }
    #pragma unroll
    for (int j = 0; j < 8; ++j) {
      float sc = __half2float(kvh[j]) + qh; sc = sc > 0.f ? sc : 0.2f * sc;
      float ex = (j < m) ? __expf(sc) : 0.f;
      den += ex;
      float2 f01 = __half22float2(*(__half2*)&uv[j].x);
      float2 f23 = __half22float2(*(__half2*)&uv[j].y);
      z.x += ex * f01.x; z.y += ex * f01.y;
      z.z += ex * f23.x; z.w += ex * f23.y;
    }
  }
  float inv = den > 0.f ? 1.f / den : 0.f;
  z.x *= inv; z.y *= inv; z.z *= inv; z.w *= inv;
  *(float4*)&z_lds[gl][h * 16 + fg * 4] = z;
  // no barrier: z_lds[gl] write+read are wave-local

  const int o = lane & 15, half = lane >> 4;
  float acc = 0.f;
  #pragma unroll
  for (int hg = 0; hg < 4; ++hg) {
    int h2 = half * 4 + hg;
    const float* zr = &z_lds[gl][h2 * 16];
    float4 z0 = *(const float4*)zr;
    float4 z1 = *(const float4*)(zr + 4);
    float4 z2 = *(const float4*)(zr + 8);
    float4 z3 = *(const float4*)(zr + 12);
    const float* wb = &Wt_lds[h2 * 256 + o];
    acc += z0.x * wb[0]   + z0.y * wb[16]  + z0.z * wb[32]  + z0.w * wb[48]
         + z1.x * wb[64]  + z1.y * wb[80]  + z1.z * wb[96]  + z1.w * wb[112]
         + z2.x * wb[128] + z2.y * wb[144] + z2.z * wb[160] + z2.w * wb[176]
         + z3.x * wb[192] + z3.y * wb[208] + z3.z * wb[224] + z3.w * wb[240];
  }
  acc += __shfl_xor(acc, 16);
  if (lane < 16) {
    float r = 0.125f * (acc + ((e1 > e0) ? bvs[o] : 0.f));
    float* ob = out + (rel ? 0 : (size_t)N_NODES * FEAT);
    ob[(size_t)node * FEAT + o] = r;
  }
}

extern "C" void kernel_launch(void* const* d_in, const int* in_sizes, int n_in,
                              void* d_out, int out_size, void* d_ws, size_t ws_size,
                              hipStream_t stream) {
  const int* idx_a  = (const int*)d_in[0];
  const int* idx_b  = (const int*)d_in[1];
  const int* src_r0 = (const int*)d_in[2];
  const int* dst_r0 = (const int*)d_in[3];
  const int* src_r1 = (const int*)d_in[4];
  const int* dst_r1 = (const int*)d_in[5];
  const float* emb_a = (const float*)d_in[6];
  const float* emb_b = (const float*)d_in[7];
  const float* l1_Wv = (const float*)d_in[8];
  const float* l1_bv = (const float*)d_in[9];
  const float* l1_Wq = (const float*)d_in[10];
  const float* l1_bq = (const float*)d_in[11];
  const float* l1_Wk = (const float*)d_in[12];
  const float* l1_bk = (const float*)d_in[13];
  const float* l2_Wv = (const float*)d_in[14];
  const float* l2_bv = (const float*)d_in[15];
  const float* l2_Wq = (const float*)d_in[16];
  const float* l2_bq = (const float*)d_in[17];
  const float* l2_Wk = (const float*)d_in[18];
  const float* l2_bk = (const float*)d_in[19];
  float* out = (float*)d_out;

  char* ws = (char*)d_ws;
  size_t off = 0;
  auto alloc = [&](size_t bytes) {
    void* p = ws + off; off += (bytes + 255) & ~255ULL; return p;
  };
  float*  u0    = (float*)alloc((size_t)N_NODES * UST * 4);
  float*  u1    = (float*)alloc((size_t)N_NODES * UST * 4);
  __half* Wt2   = (__half*)alloc(2 * 144 * 128 * 2);
  float*  b16   = (float*)alloc(2 * 16 * 4);
  float*  kb0   = (float*)alloc((size_t)N_NODES * HEADS * 4);
  float*  kb1   = (float*)alloc((size_t)N_NODES * HEADS * 4);
  float*  qb0   = (float*)alloc((size_t)N_NODES * HEADS * 4);
  float*  qb1   = (float*)alloc((size_t)N_NODES * HEADS * 4);
  __half* xk_a  = (__half*)alloc((size_t)N_NODES * XKST * 2);  // packed x+k2 fp16
  __half* xk_b  = (__half*)alloc((size_t)N_NODES * XKST * 2);
  int*    rs    = (int*)  alloc((size_t)(2 * N_NODES + 1) * 4);
  int*    cs    = (int*)  alloc((size_t)2 * NEDGE * 4);
  int*    cnt   = (int*)  alloc((size_t)4 * N_NODES * 4);
  int*    bsum  = (int*)  alloc(512 * 4);
  float*  wf    = (float*)alloc(8 * 1040 * 4);

  dim3 blk(256);
  const int n2 = 2 * N_NODES;
  int* fill = cnt + n2;
  const int nScanBlk  = (n2 + 255) / 256;
  const int nEdgeBlk2 = (2 * NEDGE + 255) / 256;
  const int nAggBlk   = (n2 + 7) / 8;
  const int nAggL2    = N_NODES / 8;
  const int nGemmBlk64 = (N_NODES + 63) / 64;
  const int nQk16Blk   = (N_NODES + 31) / 32;

  fold_kernel<<<8, blk, 0, stream>>>(l1_Wv, l1_bv, l1_Wq, l1_bq, l1_Wk, l1_bk,
                                     l2_Wv, l2_bv, l2_Wq, l2_bq, l2_Wk, l2_bk, wf);
  prep_wt2_kernel<<<2, blk, 0, stream>>>(l1_Wv, wf, Wt2, b16);
  auto wslot = [&](int layer, int rel, int qk) {
    return wf + (size_t)((layer << 2) | (rel << 1) | qk) * 1040;
  };

  hipMemsetAsync(cnt, 0, (size_t)2 * n2 * 4, stream);
  hist2_kernel<<<nEdgeBlk2, blk, 0, stream>>>(dst_r0, dst_r1, cnt);
  scan_bsum_kernel<<<nScanBlk, blk, 0, stream>>>(cnt, bsum, n2);
  scan_offsets_kernel<<<1, dim3(512), 0, stream>>>(bsum, nScanBlk);
  scan_final_kernel<<<nScanBlk, blk, 0, stream>>>(cnt, bsum, rs, n2);
  csr_scatter2_kernel<<<nEdgeBlk2, blk, 0, stream>>>(src_r0, dst_r0, src_r1, dst_r1,
                                                     rs, fill, cs);

  // ---- layer 1 (u + k + q from one MFMA kernel; agg writes fp16 x into xk) ----
  {
    gemm_mfma_kernel<<<dim3(nGemmBlk64, 2), blk, 0, stream>>>(
        emb_a, idx_a, emb_b, idx_b, Wt2, l1_bv, b16,
        u0, u1, kb0, kb1, qb1, qb0, N_NODES);
    node_agg2_kernel<<<nAggBlk, blk, 0, stream>>>(rs, cs, u0, u1, kb0, kb1,
                                                  qb0, qb1, xk_b, xk_a);
  }
  // ---- layer 2 (z-trick on packed xk rows) ----
  {
    qk16_kernel<<<dim3(nQk16Blk, 2), blk, 0, stream>>>(
        xk_a, xk_b,
        wslot(1,0,1), wslot(1,1,0), wslot(1,1,1), wslot(1,0,0),
        qb1, qb0, N_NODES);
    agg_l2z_kernel<<<dim3(nAggL2, 2), blk, 0, stream>>>(
        rs, cs, xk_a, xk_b, qb0, qb1, l2_Wv, l2_bv, out);
  }
}